// Round 9
// baseline (2501.965 us; speedup 1.0000x reference)
//
#include <hip/hip_runtime.h>

// CIN fused kernel, round 9: mfma_f32_32x32x16_f16, 4m x 2n, copy-free E/O pipeline.
// Model (fits r4-r8): per-CU pipe totals were MFMA 89us, B-frag L1 82us,
// h-LDS 41us+conflicts, VALU 30us -> near-serial 240 = r8's 248. B-bytes/MFMA
// ~ 1/m_tiles: 4m halves L1 to 41us. h from LDS (no hreg pressure), mask+2x
// folded into fprep, flat layer-0 schedule, K-loop unrolled x2 with separate
// even/odd register sets (NO rotation moves -> loads stay in flight, waitcnt
// counts nonzero). acc = 8 f32x16 = 128 AGPR; arch ~70 -> fits 256-reg tier.
// Block 256 thr = 2mg x 2ng, NB=16, grid 512 = exactly 2 blocks/CU.

#define F0N 39
#define NC16 156                              // K/16 per layer
#define LAYER_HALVES (NC16 * 4 * 64 * 8)      // 319488 f16 per layer

typedef _Float16 half8 __attribute__((ext_vector_type(8)));
typedef float f32x16 __attribute__((ext_vector_type(16)));

// Layer-0 useful chunks (c16 = 4*i + q): q=0 i<=14, q=1 i<=30, q=2 i<=37 -> 84.
__constant__ int l0_sched[86] = {
    0,1,2, 4,5,6, 8,9,10, 12,13,14, 16,17,18, 20,21,22, 24,25,26, 28,29,30,
    32,33,34, 36,37,38, 40,41,42, 44,45,46, 48,49,50, 52,53,54, 56,57,58,
    61,62, 65,66, 69,70, 73,74, 77,78, 81,82, 85,86, 89,90, 93,94, 97,98,
    101,102, 105,106, 109,110, 113,114, 117,118, 121,122,
    126, 130, 134, 138, 142, 146, 150, 150, 150};

// ---- prep: swizzle filters into 32x32x16 B-fragment order, f16 ----
// fprep[l][c16][nt][lane][reg] = F_l[row(kg), nt*32 + (lane&31)],
// kg = c16*16 + (lane>>5)*8 + reg. Layer 0: row = i*39+j (i=kg>>6, j=kg&63),
// value = 2*F0 if j>i && j<39 else 0 (triangular mask + x2 folded in).
__global__ void prep_kernel(const float* __restrict__ f0,
                            const float* __restrict__ f1,
                            const float* __restrict__ f2,
                            _Float16* __restrict__ fprep) {
    int blk  = blockIdx.x;            // l*NC16 + c16
    int l    = blk / NC16;
    int c16  = blk - l * NC16;
    int t    = threadIdx.x;
    int nt   = t >> 6;
    int lane = t & 63;
    int hf   = lane >> 5;
    int n    = nt * 32 + (lane & 31);
    const float* f = (l == 0) ? f0 : ((l == 1) ? f1 : f2);
    half8 v;
    #pragma unroll
    for (int reg = 0; reg < 8; ++reg) {
        int kg = c16 * 16 + hf * 8 + reg;
        float x;
        if (l == 0) {
            int fi = kg >> 6, fj = kg & 63;
            x = (fj > fi && fj < F0N) ? 2.0f * f[(fi * F0N + fj) * 128 + n] : 0.0f;
        } else {
            x = f[(size_t)kg * 128 + n];
        }
        v[reg] = (_Float16)x;
    }
    *(half8*)&fprep[(size_t)l * LAYER_HALVES + (((c16 * 4 + nt) * 64 + lane) << 3)] = v;
}

// Prefetch chunk C into parity-set S registers (no copies ever).
#define PREF(S, C)                                                            \
    do {                                                                      \
        int c_ = (C);                                                         \
        const _Float16* bp_ = fplw + c_ * 2048;                               \
        B##S##0 = *(const half8*)bp_;                                         \
        B##S##1 = *(const half8*)(bp_ + 512);                                 \
        int hb_ = ((c_ & 3) << 4) + (hf << 3);                                \
        h##S##0 = *(const half8*)&hT[harow0 + hb_];                           \
        h##S##1 = *(const half8*)&hT[harow1 + hb_];                           \
        h##S##2 = *(const half8*)&hT[harow2 + hb_];                           \
        h##S##3 = *(const half8*)&hT[harow3 + hb_];                           \
        int xi_ = c_ >> 2;                                                    \
        x##S##0 = xs[xrow0 + xi_];                                            \
        x##S##1 = xs[xrow1 + xi_];                                            \
        x##S##2 = xs[xrow2 + xi_];                                            \
        x##S##3 = xs[xrow3 + xi_];                                            \
    } while (0)

#define COMP(S)                                                               \
    do {                                                                      \
        half8 a0_ = h##S##0 * x##S##0;                                        \
        half8 a1_ = h##S##1 * x##S##1;                                        \
        half8 a2_ = h##S##2 * x##S##2;                                        \
        half8 a3_ = h##S##3 * x##S##3;                                        \
        a00 = __builtin_amdgcn_mfma_f32_32x32x16_f16(a0_, B##S##0, a00, 0, 0, 0); \
        a01 = __builtin_amdgcn_mfma_f32_32x32x16_f16(a0_, B##S##1, a01, 0, 0, 0); \
        a10 = __builtin_amdgcn_mfma_f32_32x32x16_f16(a1_, B##S##0, a10, 0, 0, 0); \
        a11 = __builtin_amdgcn_mfma_f32_32x32x16_f16(a1_, B##S##1, a11, 0, 0, 0); \
        a20 = __builtin_amdgcn_mfma_f32_32x32x16_f16(a2_, B##S##0, a20, 0, 0, 0); \
        a21 = __builtin_amdgcn_mfma_f32_32x32x16_f16(a2_, B##S##1, a21, 0, 0, 0); \
        a30 = __builtin_amdgcn_mfma_f32_32x32x16_f16(a3_, B##S##0, a30, 0, 0, 0); \
        a31 = __builtin_amdgcn_mfma_f32_32x32x16_f16(a3_, B##S##1, a31, 0, 0, 0); \
    } while (0)

// Epilogue for one 32x32 tile: TT = n-tile (0/1), NB0 = base batch of m-tile.
#define EPILOGUE_TILE(ACC, TT, NB0, CM0, CM1)                                 \
    do {                                                                      \
        float r[16];                                                          \
        _Pragma("unroll")                                                     \
        for (int reg = 0; reg < 16; ++reg)                                    \
            r[reg] = fmaxf((ACC)[reg], 0.0f);                                 \
        if (layer < 2 && ng == 0) {                                           \
            const int j = (TT) * 32 + lane5;                                  \
            _Pragma("unroll")                                                 \
            for (int reg = 0; reg < 16; ++reg) {                              \
                int nb = (NB0) + (reg >> 3);                                  \
                int d  = (reg & 3) + 8 * ((reg >> 2) & 1) + 4 * hf;           \
                hT[(nb * 16 + d) * 72 + j] = (_Float16)r[reg];                \
            }                                                                 \
        }                                                                     \
        if (layer == 2 || ng == 1) {                                          \
            const float w = 1.0f + wnn[catbase + (ng * 2 + (TT)) * 32 + lane5]; \
            float s0 = ((r[0] + r[1]) + (r[2] + r[3])) +                      \
                       ((r[4] + r[5]) + (r[6] + r[7]));                       \
            float s1 = ((r[8] + r[9]) + (r[10] + r[11])) +                    \
                       ((r[12] + r[13]) + (r[14] + r[15]));                   \
            s0 += __shfl_xor(s0, 32, 64);                                     \
            s1 += __shfl_xor(s1, 32, 64);                                     \
            CM0 = fmaf(s0, w, CM0);                                           \
            CM1 = fmaf(s1, w, CM1);                                           \
        }                                                                     \
    } while (0)

#define EPI_MT(ACC0, ACC1, MT)                                                \
    do {                                                                      \
        const int nb0 = mg * 8 + (MT) * 2;                                    \
        float cm0 = 0.0f, cm1 = 0.0f;                                         \
        EPILOGUE_TILE(ACC0, 0, nb0, cm0, cm1);                                \
        EPILOGUE_TILE(ACC1, 1, nb0, cm0, cm1);                                \
        _Pragma("unroll")                                                     \
        for (int sh = 16; sh >= 1; sh >>= 1) {                                \
            cm0 += __shfl_xor(cm0, sh, 64);                                   \
            cm1 += __shfl_xor(cm1, sh, 64);                                   \
        }                                                                     \
        if (lane == 0 && (layer == 2 || ng == 1)) {                           \
            atomicAdd(&outacc[nb0], cm0);                                     \
            atomicAdd(&outacc[nb0 + 1], cm1);                                 \
        }                                                                     \
    } while (0)

#define ZERO16(A) { _Pragma("unroll") for (int e = 0; e < 16; ++e) (A)[e] = 0.0f; }

__global__ __launch_bounds__(256, 2) void cin_mfma(
    const float* __restrict__ xin,     // (B, 624) fp32
    const _Float16* __restrict__ fprep,
    const float* __restrict__ wnn,     // (256)
    const float* __restrict__ bnn,     // (1)
    float* __restrict__ out)           // (B)
{
    __shared__ _Float16 hT[16 * 16 * 72] __attribute__((aligned(16)));  // [nb][d][j pad72] 36864 B
    __shared__ _Float16 xs[16 * 16 * 40] __attribute__((aligned(16)));  // [nb][d][i pad40] 20480 B
    __shared__ float outacc[16];

    const int t     = threadIdx.x;
    const int wave  = t >> 6;        // 0..3
    const int lane  = t & 63;
    const int hf    = lane >> 5;     // k-half within 16-chunk
    const int lane5 = lane & 31;
    const int dl    = lane & 15;     // d for A-side
    const int bt    = lane5 >> 4;    // A-side batch within 32-row m-tile
    const int mg    = wave >> 1;     // m-group: batches mg*8 .. +8
    const int ng    = wave & 1;      // n-half:  cols ng*64 .. +64
    const int b0    = blockIdx.x * 16;

    // zero hT (j-pad must be 0)
    for (int u = t; u < 2304; u += 256) ((uint4*)hT)[u] = uint4{0, 0, 0, 0};
    if (t < 16) outacc[t] = 0.0f;
    __syncthreads();

    // stage x0 -> hT (layer-0 hidden, [nb][d][j=i]) and xs ([nb][d][i])
    for (int u = t; u < 16 * F0N; u += 256) {
        int nb = u / F0N;
        int i  = u - nb * F0N;
        const float* src = xin + (size_t)(b0 + nb) * 624 + i * 16;
        #pragma unroll
        for (int q = 0; q < 4; ++q) {
            float4 v = *(const float4*)(src + q * 4);
            int d = q * 4;
            hT[(nb * 16 + d + 0) * 72 + i] = (_Float16)v.x;
            hT[(nb * 16 + d + 1) * 72 + i] = (_Float16)v.y;
            hT[(nb * 16 + d + 2) * 72 + i] = (_Float16)v.z;
            hT[(nb * 16 + d + 3) * 72 + i] = (_Float16)v.w;
            xs[(nb * 16 + d + 0) * 40 + i] = (_Float16)v.x;
            xs[(nb * 16 + d + 1) * 40 + i] = (_Float16)v.y;
            xs[(nb * 16 + d + 2) * 40 + i] = (_Float16)v.z;
            xs[(nb * 16 + d + 3) * 40 + i] = (_Float16)v.w;
        }
    }
    __syncthreads();

    // lane's four A-rows (m-tiles 0..3): batches mg*8 + mt*2 + bt, d = dl
    const int arow0  = (mg * 8 + 0 + bt) * 16 + dl;
    const int arow1  = (mg * 8 + 2 + bt) * 16 + dl;
    const int arow2  = (mg * 8 + 4 + bt) * 16 + dl;
    const int arow3  = (mg * 8 + 6 + bt) * 16 + dl;
    const int harow0 = arow0 * 72, harow1 = arow1 * 72;
    const int harow2 = arow2 * 72, harow3 = arow3 * 72;
    const int xrow0  = arow0 * 40, xrow1 = arow1 * 40;
    const int xrow2  = arow2 * 40, xrow3 = arow3 * 40;

    for (int layer = 0; layer < 3; ++layer) {
        f32x16 a00, a01, a10, a11, a20, a21, a30, a31;
        ZERO16(a00); ZERO16(a01); ZERO16(a10); ZERO16(a11);
        ZERO16(a20); ZERO16(a21); ZERO16(a30); ZERO16(a31);

        // wave's B base: frag (c16,tt) at fplw + c16*2048 + tt*512 (halves)
        const _Float16* fplw = fprep + (size_t)layer * LAYER_HALVES
                             + ng * 1024 + (lane << 3);

        half8 BE0, BE1, BO0, BO1;
        half8 hE0, hE1, hE2, hE3, hO0, hO1, hO2, hO3;
        _Float16 xE0, xE1, xE2, xE3, xO0, xO1, xO2, xO3;

        if (layer == 0) {
            PREF(E, l0_sched[0]);
            PREF(O, l0_sched[1]);
            for (int s = 0; s <= 80; s += 2) {
                COMP(E);
                PREF(E, l0_sched[s + 2]);
                COMP(O);
                PREF(O, l0_sched[s + 3]);
            }
            COMP(E);
            COMP(O);
        } else {
            PREF(E, 0);
            PREF(O, 1);
            for (int c = 0; c <= 152; c += 2) {
                COMP(E);
                PREF(E, c + 2);
                COMP(O);
                PREF(O, c + 3);
            }
            COMP(E);
            COMP(O);
        }

        __syncthreads();   // all hT reads of this layer done before overwrite

        // C/D layout: col n = (ng*2+tt)*32 + lane5;
        // row = (reg&3) + 8*(reg>>2) + 4*hf -> batch_in_tile = reg>>3,
        // d = (reg&3) + 8*((reg>>2)&1) + 4*hf.
        const int catbase = (layer == 2) ? 128 : ((layer == 0) ? -64 : 0);
        EPI_MT(a00, a01, 0);
        EPI_MT(a10, a11, 1);
        EPI_MT(a20, a21, 2);
        EPI_MT(a30, a31, 3);
        __syncthreads();   // hT(next hidden) + outacc visible
    }

    if (t < 16) out[b0 + t] = outacc[t] + bnn[0];
}

extern "C" void kernel_launch(void* const* d_in, const int* in_sizes, int n_in,
                              void* d_out, int out_size, void* d_ws, size_t ws_size,
                              hipStream_t stream) {
    const float* xin = (const float*)d_in[0];
    const float* f0g = (const float*)d_in[1];
    const float* f1g = (const float*)d_in[2];
    const float* f2g = (const float*)d_in[3];
    const float* wnn = (const float*)d_in[4];
    const float* bnn = (const float*)d_in[5];
    float* out = (float*)d_out;
    _Float16* fprep = (_Float16*)d_ws;   // 3 * 319488 * 2 B = 1.83 MB

    prep_kernel<<<3 * NC16, 256, 0, stream>>>(f0g, f1g, f2g, fprep);

    const int B = in_sizes[0] / 624;     // 8192
    cin_mfma<<<B / 16, 256, 0, stream>>>(xin, fprep, wnn, bnn, out);
}